// Round 15
// baseline (193.595 us; speedup 1.0000x reference)
//
#include <hip/hip_runtime.h>

// ---------------------------------------------------------------------------
// Round 15: revert head-split (r14 regressed: fixed per-edge costs doubled).
// Attack the load-imbalance tail instead:
//  - k_degsort: single-block counting sort of nodes by degree (97 bins).
//  - agg: wave-stride over degree-sorted order, exactly 2048 blocks
//    (8192 waves = 8/SIMD). Co-resident waves get equal-degree nodes ->
//    blocks retire together. att hoisted out of node loop.
//  - per-node math identical to round 13 (bitwise-same output).
// ---------------------------------------------------------------------------

typedef _Float16 half2v __attribute__((ext_vector_type(2)));
typedef _Float16 half8v __attribute__((ext_vector_type(8)));
typedef __attribute__((ext_vector_type(4))) float floatx4;

#define SLOT_STRIDE 96
#define AGG_BLOCKS 2048

template <int CPL> struct VecSel;
template <> struct VecSel<4> { using T = uint2; };
template <> struct VecSel<8> { using T = uint4; };

__device__ inline unsigned short f2h(float v) {
    return __builtin_bit_cast(unsigned short, (_Float16)v);
}
__device__ inline half2v u2h2(unsigned u) { return __builtin_bit_cast(half2v, u); }
__device__ inline unsigned h22u(half2v h) { return __builtin_bit_cast(unsigned, h); }
__device__ inline unsigned packh2(float a, float b) {
    half2v h; h[0] = (_Float16)a; h[1] = (_Float16)b;
    return h22u(h);
}

__device__ inline float fdot2f(half2v a, half2v b, float c) {
#if __has_builtin(__builtin_amdgcn_fdot2)
    return __builtin_amdgcn_fdot2(a, b, c, false);
#else
    return c + (float)a[0] * (float)b[0] + (float)a[1] * (float)b[1];
#endif
}

// ---------------- fused setup: scatter(padded CSR) + l1 + wconv + goff -----

#define L1_NODES 32

__global__ void k_setup(const int* __restrict__ ei, int E0, int N, int B,
                        int* __restrict__ counts, int* __restrict__ slots,
                        const int* __restrict__ batch, int* __restrict__ goff,
                        const float* __restrict__ x,
                        const float* __restrict__ Wl1, const float* __restrict__ bl1,
                        const float* __restrict__ Wr1, const float* __restrict__ br1,
                        unsigned short* __restrict__ xl1, unsigned short* __restrict__ xr1,
                        const float* __restrict__ Wl2, const float* __restrict__ Wr2,
                        unsigned short* __restrict__ Wlt, unsigned short* __restrict__ Wrt) {
    __shared__ char smem[8320];
    int E = E0 + N;
    int SC = (E + 255) >> 8;
    int L1B = (N + L1_NODES - 1) / L1_NODES;
    int bid = blockIdx.x;
    int t = threadIdx.x;  // 256

    if (bid < SC) {
        int e = bid * 256 + t;
        if (e >= E) return;
        int s, d;
        if (e < E0) { s = ei[e]; d = ei[E0 + e]; } else { s = e - E0; d = s; }
        int pos = atomicAdd(&counts[d], 1);
        if (pos < SLOT_STRIDE) slots[d * SLOT_STRIDE + pos] = s;
    } else if (bid < SC + L1B) {
        float (*xs)[9] = reinterpret_cast<float(*)[9]>(smem);
        int nb = (bid - SC) * L1_NODES;
        int h = t >> 7, p = t & 127;
        for (int i = t; i < L1_NODES * 9; i += 256) {
            int node = nb + i / 9;
            xs[i / 9][i % 9] = (node < N) ? x[node * 9 + i % 9] : 0.f;
        }
        __syncthreads();
        int c0 = 2 * p, c1 = 2 * p + 1;
        float wl0[9], wl1[9], wr0[9], wr1[9];
#pragma unroll
        for (int k = 0; k < 9; k++) {
            wl0[k] = Wl1[k * 256 + c0]; wl1[k] = Wl1[k * 256 + c1];
            wr0[k] = Wr1[k * 256 + c0]; wr1[k] = Wr1[k * 256 + c1];
        }
        float b0 = bl1[c0], b1 = bl1[c1], r0b = br1[c0], r1b = br1[c1];
        for (int j = h * 16; j < h * 16 + 16; j++) {
            int node = nb + j;
            if (node >= N) break;
            float a0 = b0, a1 = b1, r0 = r0b, r1 = r1b;
#pragma unroll
            for (int k = 0; k < 9; k++) {
                float xv = xs[j][k];
                a0 += xv * wl0[k]; a1 += xv * wl1[k];
                r0 += xv * wr0[k]; r1 += xv * wr1[k];
            }
            *reinterpret_cast<unsigned*>(xl1 + (size_t)node * 256 + c0) = packh2(a0, a1);
            *reinterpret_cast<unsigned*>(xr1 + (size_t)node * 256 + c0) = packh2(r0, r1);
        }
    } else if (bid < SC + L1B + 64) {
        unsigned short (*tile)[65] = reinterpret_cast<unsigned short(*)[65]>(smem);
        int idx = bid - SC - L1B;
        int tx = idx & 7, ty = (idx >> 3) & 3, tz = idx >> 5;
        const float* W = tz ? Wr2 : Wl2;
        unsigned short* Wt = tz ? Wrt : Wlt;
        int k0 = ty * 64, n0 = tx * 64;
        int tn = t & 63, tq = t >> 6;
#pragma unroll
        for (int i = 0; i < 16; i++) {
            int k = tq * 16 + i;
            tile[k][tn] = f2h(W[(size_t)(k0 + k) * 512 + n0 + tn]);
        }
        __syncthreads();
#pragma unroll
        for (int i = 0; i < 16; i++) {
            int nn = tq * 16 + i;
            Wt[(size_t)(n0 + nn) * 256 + k0 + tn] = tile[tn][nn];
        }
    } else {
        int n = (bid - SC - L1B - 64) * 256 + t;
        if (n >= N) return;
        int b = batch[n];
        int prev = (n == 0) ? -1 : batch[n - 1];
        for (int g = prev + 1; g <= b; g++) goff[g] = n;
        if (n == N - 1)
            for (int g = b + 1; g <= B; g++) goff[g] = N;
    }
}

// ---------------- degree counting sort (single block) ----------------
// order[] = node ids grouped by degree; per-node results are independent so
// any within-bin order yields identical output.

__global__ void k_degsort(const int* __restrict__ counts, int* __restrict__ order, int N) {
    __shared__ int bins[128];
    __shared__ int base[128];
    int t = threadIdx.x;  // 1024
    if (t < 128) bins[t] = 0;
    __syncthreads();
    for (int n = t; n < N; n += 1024) {
        int d = counts[n]; d = d > 96 ? 96 : d;
        atomicAdd(&bins[d], 1);
    }
    __syncthreads();
    if (t == 0) {
        int s = 0;
        for (int i = 0; i < 128; i++) { base[i] = s; s += bins[i]; }
    }
    __syncthreads();
    if (t < 128) bins[t] = 0;  // reuse as cursors
    __syncthreads();
    for (int n = t; n < N; n += 1024) {
        int d = counts[n]; d = d > 96 ? 96 : d;
        int p = atomicAdd(&bins[d], 1);
        order[base[d] + p] = n;
    }
}

// ---------------- wave-stride GATv2 aggregation over sorted order ----------
// dual-edge iteration, f16 packed acc, defer-max THR=4. CPL ch/lane.

template <int CPL>
__global__ __launch_bounds__(256) void k_gat_agg(
        const unsigned short* __restrict__ xl,
        const unsigned short* __restrict__ xr,
        const float* __restrict__ att, const float* __restrict__ bias,
        const float* __restrict__ gamma, const float* __restrict__ beta,
        const float* __restrict__ mean, const float* __restrict__ var,
        const int* __restrict__ counts, const int* __restrict__ slots,
        const int* __restrict__ order,
        unsigned short* __restrict__ hout, int N) {
    const int HC = 64 * CPL;
    const int V = CPL / 2;
    using VecT = typename VecSel<CPL>::T;
    int gw = (blockIdx.x * blockDim.x + threadIdx.x) >> 6;
    int lane = threadIdx.x & 63;
    const int GW = AGG_BLOCKS * 4;  // total waves
    int cbase = lane * CPL;

    half2v at2[V];
#pragma unroll
    for (int v = 0; v < V; v++) {
        at2[v][0] = (_Float16)att[cbase + 2 * v];
        at2[v][1] = (_Float16)att[cbase + 2 * v + 1];
    }
    const half2v c02 = {(_Float16)0.2f, (_Float16)0.2f};

    for (int i = gw; i < N; i += GW) {
        int n = order[i];
        half2v xr2[V], acc[V];
        {
            VecT q = *reinterpret_cast<const VecT*>(xr + (size_t)n * HC + cbase);
            unsigned r[V];
            if constexpr (CPL == 8) { r[0] = q.x; r[1] = q.y; r[2] = q.z; r[3] = q.w; }
            else { r[0] = q.x; r[1] = q.y; }
#pragma unroll
            for (int v = 0; v < V; v++) {
                xr2[v] = u2h2(r[v]);
                acc[v] = (half2v){(_Float16)0.f, (_Float16)0.f};
            }
        }
        int deg = counts[n];
        deg = deg < SLOT_STRIDE ? deg : SLOT_STRIDE;
        const int* sl = slots + (size_t)n * SLOT_STRIDE;
        const unsigned short* xlb = xl + cbase;
        float m = -1e30f, l = 0.f;

        VecT qA = *reinterpret_cast<const VecT*>(xlb + (size_t)sl[0] * HC);
        VecT qB = (deg > 1) ? *reinterpret_cast<const VecT*>(xlb + (size_t)sl[1] * HC) : qA;

        int slot = 0;
        while (slot + 1 < deg) {
            VecT ra = qA, rb = qB;
            int p2 = slot + 2 < deg ? slot + 2 : deg - 1;
            int p3 = slot + 3 < deg ? slot + 3 : deg - 1;
            qA = *reinterpret_cast<const VecT*>(xlb + (size_t)sl[p2] * HC);
            qB = *reinterpret_cast<const VecT*>(xlb + (size_t)sl[p3] * HC);

            half2v ah[V], bh[V];
            {
                unsigned ua[V], ub[V];
                if constexpr (CPL == 8) {
                    ua[0] = ra.x; ua[1] = ra.y; ua[2] = ra.z; ua[3] = ra.w;
                    ub[0] = rb.x; ub[1] = rb.y; ub[2] = rb.z; ub[3] = rb.w;
                } else {
                    ua[0] = ra.x; ua[1] = ra.y;
                    ub[0] = rb.x; ub[1] = rb.y;
                }
#pragma unroll
                for (int v = 0; v < V; v++) { ah[v] = u2h2(ua[v]); bh[v] = u2h2(ub[v]); }
            }
            float pa = 0.f, pb = 0.f;
#pragma unroll
            for (int v = 0; v < V; v++) {
                half2v ta = ah[v] + xr2[v];
                half2v la = __builtin_elementwise_max(ta, ta * c02);
                pa = fdot2f(la, at2[v], pa);
                half2v tb = bh[v] + xr2[v];
                half2v lb = __builtin_elementwise_max(tb, tb * c02);
                pb = fdot2f(lb, at2[v], pb);
            }
            pa += __shfl_xor(pa, 1);  pb += __shfl_xor(pb, 1);
            pa += __shfl_xor(pa, 2);  pb += __shfl_xor(pb, 2);
            pa += __shfl_xor(pa, 4);  pb += __shfl_xor(pb, 4);
            pa += __shfl_xor(pa, 8);  pb += __shfl_xor(pb, 8);
            float pm = fmaxf(pa, pb);
            if (__all(pm <= m + 4.f)) {
                float wa = __expf(pa - m), wb = __expf(pb - m);
                l += wa + wb;
                _Float16 wah = (_Float16)wa, wbh = (_Float16)wb;
                half2v wa2 = {wah, wah}, wb2 = {wbh, wbh};
#pragma unroll
                for (int v = 0; v < V; v++) {
                    acc[v] = ah[v] * wa2 + acc[v];
                    acc[v] = bh[v] * wb2 + acc[v];
                }
            } else {
                float mn = fmaxf(m, pm);
                float sc = __expf(m - mn);
                float wa = __expf(pa - mn), wb = __expf(pb - mn);
                l = l * sc + wa + wb;
                _Float16 sch = (_Float16)sc, wah = (_Float16)wa, wbh = (_Float16)wb;
                half2v sc2 = {sch, sch}, wa2 = {wah, wah}, wb2 = {wbh, wbh};
#pragma unroll
                for (int v = 0; v < V; v++) {
                    acc[v] = ah[v] * wa2 + acc[v] * sc2;
                    acc[v] = bh[v] * wb2 + acc[v];
                }
                m = mn;
            }
            slot += 2;
        }
        if (slot < deg) {
            half2v ah[V];
            {
                unsigned ua[V];
                if constexpr (CPL == 8) {
                    ua[0] = qA.x; ua[1] = qA.y; ua[2] = qA.z; ua[3] = qA.w;
                } else {
                    ua[0] = qA.x; ua[1] = qA.y;
                }
#pragma unroll
                for (int v = 0; v < V; v++) ah[v] = u2h2(ua[v]);
            }
            float pa = 0.f;
#pragma unroll
            for (int v = 0; v < V; v++) {
                half2v ta = ah[v] + xr2[v];
                half2v la = __builtin_elementwise_max(ta, ta * c02);
                pa = fdot2f(la, at2[v], pa);
            }
            pa += __shfl_xor(pa, 1);
            pa += __shfl_xor(pa, 2);
            pa += __shfl_xor(pa, 4);
            pa += __shfl_xor(pa, 8);
            if (__all(pa <= m + 4.f)) {
                float wa = __expf(pa - m);
                l += wa;
                _Float16 wah = (_Float16)wa;
                half2v wa2 = {wah, wah};
#pragma unroll
                for (int v = 0; v < V; v++) acc[v] = ah[v] * wa2 + acc[v];
            } else {
                float mn = fmaxf(m, pa);
                float sc = __expf(m - mn);
                float wa = __expf(pa - mn);
                l = l * sc + wa;
                _Float16 sch = (_Float16)sc, wah = (_Float16)wa;
                half2v sc2 = {sch, sch}, wa2 = {wah, wah};
#pragma unroll
                for (int v = 0; v < V; v++) acc[v] = ah[v] * wa2 + acc[v] * sc2;
                m = mn;
            }
        }

        float inv = 1.f / l;
        unsigned ow[V];
#pragma unroll
        for (int v = 0; v < V; v++) {
            half2v o;
#pragma unroll
            for (int j = 0; j < 2; j++) {
                int c = cbase + 2 * v + j;
                float val = (float)acc[v][j] * inv + bias[c];
                val = (val - mean[c]) * rsqrtf(var[c] + 1e-5f) * gamma[c] + beta[c];
                o[j] = (_Float16)fmaxf(val, 0.f);
            }
            ow[v] = h22u(o);
        }
        unsigned short* dst = hout + (size_t)n * HC + cbase;
        if constexpr (CPL == 8)
            *reinterpret_cast<uint4*>(dst) = *reinterpret_cast<uint4*>(ow);
        else
            *reinterpret_cast<uint2*>(dst) = *reinterpret_cast<uint2*>(ow);
    }
}

// ---------------- f16 MFMA GEMM: C[M,512] = A[M,256] @ Wt^T + bias --------

__global__ __launch_bounds__(256) void k_gemm_mfma(
    const unsigned short* __restrict__ A,    // [M][256] f16
    const unsigned short* __restrict__ Wlt,  // [512][256] f16
    const unsigned short* __restrict__ Wrt,
    const float* __restrict__ bl, const float* __restrict__ br,
    unsigned short* __restrict__ Cl, unsigned short* __restrict__ Cr,
    int M) {
    const int K = 256, NCOL = 512;
    __shared__ unsigned short lds[2][2][128 * 32];  // [buf][A|B][row*32+k], 32KB
    int side = blockIdx.z;
    const unsigned short* Bmat = side ? Wrt : Wlt;
    const float* bias = side ? br : bl;
    unsigned short* C = side ? Cr : Cl;
    int bm = blockIdx.y * 128, bn = blockIdx.x * 128;
    int t = threadIdx.x;
    int lane = t & 63;
    int wid = t >> 6;
    int wr = wid >> 1, wc = wid & 1;

    floatx4 acc[4][4];
#pragma unroll
    for (int m = 0; m < 4; m++)
#pragma unroll
        for (int n = 0; n < 4; n++) acc[m][n] = (floatx4){0.f, 0.f, 0.f, 0.f};

    auto stage = [&](int buf, int k0) {
#pragma unroll
        for (int i = 0; i < 2; i++) {
            int c = i * 256 + t;            // 16B chunk id, 512 chunks per tile
            int row = c >> 2;               // tile row (0..127)
            int kk = ((c & 3) << 3) ^ (((row >> 1) & 3) << 3);  // swizzled k-elems
            int gm = bm + row; gm = gm < M ? gm : M - 1;
            const unsigned short* gA = A + (size_t)gm * K + k0 + kk;
            __builtin_amdgcn_global_load_lds(
                (const __attribute__((address_space(1))) void*)gA,
                (__attribute__((address_space(3))) void*)&lds[buf][0][c * 8], 16, 0, 0);
            int gn = bn + row;
            const unsigned short* gB = Bmat + (size_t)gn * K + k0 + kk;
            __builtin_amdgcn_global_load_lds(
                (const __attribute__((address_space(1))) void*)gB,
                (__attribute__((address_space(3))) void*)&lds[buf][1][c * 8], 16, 0, 0);
        }
    };

    stage(0, 0);
    __syncthreads();
    int q = lane >> 4, rl = lane & 15;
    for (int ks = 0; ks < 8; ks++) {
        int buf = ks & 1;
        if (ks < 7) stage(buf ^ 1, (ks + 1) * 32);
        half8v a[4], b[4];
#pragma unroll
        for (int m = 0; m < 4; m++) {
            int row = wr * 64 + m * 16 + rl;
            int colb = (q * 16) ^ (((row >> 1) & 3) << 4);  // byte offset in row
            a[m] = *reinterpret_cast<const half8v*>(
                reinterpret_cast<const char*>(&lds[buf][0][0]) + row * 64 + colb);
        }
#pragma unroll
        for (int n = 0; n < 4; n++) {
            int row = wc * 64 + n * 16 + rl;
            int colb = (q * 16) ^ (((row >> 1) & 3) << 4);
            b[n] = *reinterpret_cast<const half8v*>(
                reinterpret_cast<const char*>(&lds[buf][1][0]) + row * 64 + colb);
        }
#pragma unroll
        for (int m = 0; m < 4; m++)
#pragma unroll
            for (int n = 0; n < 4; n++)
                acc[m][n] = __builtin_amdgcn_mfma_f32_16x16x32_f16(a[m], b[n], acc[m][n], 0, 0, 0);
        __syncthreads();
    }
    // epilogue: C/D layout col = lane&15, row = (lane>>4)*4 + reg
#pragma unroll
    for (int m = 0; m < 4; m++) {
#pragma unroll
        for (int n = 0; n < 4; n++) {
            int gn = bn + wc * 64 + n * 16 + rl;
            float bv = bias[gn];
#pragma unroll
            for (int r = 0; r < 4; r++) {
                int gm = bm + wr * 64 + m * 16 + q * 4 + r;
                if (gm < M) C[(size_t)gm * NCOL + gn] = f2h(acc[m][n][r] + bv);
            }
        }
    }
}

// ---------------- pooling phase 1 (B x 32 chunks, deterministic) -----------

#define POOL_CHUNKS 32

__global__ void k_pool_partial(const unsigned short* __restrict__ h2,
                               const int* __restrict__ goff,
                               float* __restrict__ partial) {
    int g = blockIdx.x, c = blockIdx.y;
    int t = threadIdx.x;  // 256, each handles 2 cols via uint load
    int n0 = goff[g], n1 = goff[g + 1];
    int len = n1 - n0;
    int c0 = n0 + (int)(((long long)len * c) / POOL_CHUNKS);
    int c1 = n0 + (int)(((long long)len * (c + 1)) / POOL_CHUNKS);
    float s0 = 0.f, s1 = 0.f;
    for (int n = c0; n < c1; n++) {
        half2v h = u2h2(*reinterpret_cast<const unsigned*>(h2 + (size_t)n * 512 + t * 2));
        s0 += (float)h[0]; s1 += (float)h[1];
    }
    float* p = partial + ((size_t)g * POOL_CHUNKS + c) * 512;
    p[t * 2] = s0;
    p[t * 2 + 1] = s1;
}

// ---------------- fused pool-combine + MLP head (one block per graph) ------

__global__ void k_pool_head(const float* __restrict__ partial,
                            const int* __restrict__ goff,
                            const float* __restrict__ gf,
                            const float* __restrict__ W1, const float* __restrict__ b1,
                            const float* __restrict__ W2, const float* __restrict__ b2,
                            float* __restrict__ out) {
    int g = blockIdx.x;
    int t = threadIdx.x;  // 512
    __shared__ float z[532];
    __shared__ float red[128];
    float s = 0.f;
#pragma unroll
    for (int c = 0; c < POOL_CHUNKS; c++)
        s += partial[((size_t)g * POOL_CHUNKS + c) * 512 + t];
    float inv = 1.f / fmaxf((float)(goff[g + 1] - goff[g]), 1.f);
    z[t] = s * inv;
    if (t < 20) z[512 + t] = gf[g * 20 + t];
    __syncthreads();
    if (t < 128) {
        float a = b1[t];
        for (int k = 0; k < 532; k++) a += z[k] * W1[k * 128 + t];
        red[t] = fmaxf(a, 0.f) * W2[t];
    }
    __syncthreads();
    if (t < 64) {
        float v = red[t] + red[t + 64];
#pragma unroll
        for (int sdown = 32; sdown; sdown >>= 1) v += __shfl_down(v, sdown);
        if (t == 0) out[g] = v + b2[0];
    }
}

// ---------------------------------------------------------------------------

extern "C" void kernel_launch(void* const* d_in, const int* in_sizes, int n_in,
                              void* d_out, int out_size, void* d_ws, size_t ws_size,
                              hipStream_t stream) {
    const float* x       = (const float*)d_in[0];
    const float* gfeat   = (const float*)d_in[1];
    const int*   ei      = (const int*)d_in[2];
    const int*   batch   = (const int*)d_in[3];
    const float* W_l1    = (const float*)d_in[4];
    const float* b_l1    = (const float*)d_in[5];
    const float* W_r1    = (const float*)d_in[6];
    const float* b_r1    = (const float*)d_in[7];
    const float* att1    = (const float*)d_in[8];
    const float* bias1   = (const float*)d_in[9];
    const float* bn1_g   = (const float*)d_in[10];
    const float* bn1_b   = (const float*)d_in[11];
    const float* bn1_m   = (const float*)d_in[12];
    const float* bn1_v   = (const float*)d_in[13];
    const float* W_l2    = (const float*)d_in[14];
    const float* b_l2    = (const float*)d_in[15];
    const float* W_r2    = (const float*)d_in[16];
    const float* b_r2    = (const float*)d_in[17];
    const float* att2    = (const float*)d_in[18];
    const float* bias2   = (const float*)d_in[19];
    const float* bn2_g   = (const float*)d_in[20];
    const float* bn2_b   = (const float*)d_in[21];
    const float* bn2_m   = (const float*)d_in[22];
    const float* bn2_v   = (const float*)d_in[23];
    const float* fc1_W   = (const float*)d_in[24];
    const float* fc1_b   = (const float*)d_in[25];
    const float* fc2_W   = (const float*)d_in[26];
    const float* fc2_b   = (const float*)d_in[27];
    float* out = (float*)d_out;

    const int N  = in_sizes[0] / 9;   // 20000
    const int B  = in_sizes[1] / 20;  // 64
    const int E0 = in_sizes[2] / 2;   // 320000
    const int E  = E0 + N;

    // ---- workspace layout (bytes) ----
    char* ws = (char*)d_ws;
    const size_t SZ256 = (size_t)N * 256 * 2;  // 10.24 MB (f16)
    const size_t SZ512 = (size_t)N * 512 * 2;  // 20.48 MB (f16)
    unsigned short* xl1 = (unsigned short*)(ws);
    unsigned short* xr1 = (unsigned short*)(ws + SZ256);
    unsigned short* h1  = (unsigned short*)(ws + 2 * SZ256);
    unsigned short* xl2 = (unsigned short*)(ws + 3 * SZ256);
    unsigned short* xr2 = (unsigned short*)(ws + 3 * SZ256 + SZ512);
    unsigned short* h2  = (unsigned short*)(ws + 3 * SZ256 + 2 * SZ512);
    size_t o = 3 * SZ256 + 3 * SZ512;                       // 92,160,000
    unsigned short* Wlt = (unsigned short*)(ws + o);        // 512*256*2 = 262144
    unsigned short* Wrt = (unsigned short*)(ws + o + 262144);
    size_t oi = o + 2 * 262144;                             // 92,684,288
    int* counts = (int*)(ws + oi);                          // N ints (zeroed)
    int* goff   = (int*)(ws + oi + 80000);                  // B+1 ints
    int* order  = (int*)(ws + oi + 80000 + 384);            // N ints
    int* slots  = (int*)(ws + oi + 80000 + 384 + 80000);    // N*96 ints = 7.68MB
    size_t op = oi + 80000 + 384 + 80000 + (size_t)N * SLOT_STRIDE * 4;
    float* partial = (float*)(ws + op);                     // B*32*512 f32 = 4MB
    (void)ws_size; (void)n_in; (void)out_size;

    (void)hipMemsetAsync(ws + oi, 0, 80000, stream);

    // fused setup: scatter + l1_transform + wconv + goff
    int SC = (E + 255) / 256;
    int L1B = (N + L1_NODES - 1) / L1_NODES;
    int GB = (N + 255) / 256;
    k_setup<<<SC + L1B + 64 + GB, 256, 0, stream>>>(
        ei, E0, N, B, counts, slots, batch, goff,
        x, W_l1, b_l1, W_r1, b_r1, xl1, xr1, W_l2, W_r2, Wlt, Wrt);

    // degree counting sort (load balance for wave-stride agg)
    k_degsort<<<1, 1024, 0, stream>>>(counts, order, N);

    // layer 1 aggregation (CPL=4, HC=256)
    k_gat_agg<4><<<AGG_BLOCKS, 256, 0, stream>>>(
        xl1, xr1, att1, bias1, bn1_g, bn1_b, bn1_m, bn1_v, counts, slots, order, h1, N);

    // layer 2 transforms: one dispatch, z selects W_l / W_r
    dim3 ggrid(512 / 128, (N + 127) / 128, 2);
    k_gemm_mfma<<<ggrid, 256, 0, stream>>>(h1, Wlt, Wrt, b_l2, b_r2, xl2, xr2, N);

    // layer 2 aggregation (CPL=8, HC=512)
    k_gat_agg<8><<<AGG_BLOCKS, 256, 0, stream>>>(
        xl2, xr2, att2, bias2, bn2_g, bn2_b, bn2_m, bn2_v, counts, slots, order, h2, N);

    // pool (partial) + fused combine+head
    k_pool_partial<<<dim3(B, POOL_CHUNKS), 256, 0, stream>>>(h2, goff, partial);
    k_pool_head<<<B, 512, 0, stream>>>(partial, goff, gfeat,
                                       fc1_W, fc1_b, fc2_W, fc2_b, out);
}

// Round 16
// 170.301 us; speedup vs baseline: 1.1368x; 1.1368x over previous
//
#include <hip/hip_runtime.h>

// ---------------------------------------------------------------------------
// Round 16 = exact revert to round 13 (best known: 170.2us, absmax 2.4e-4).
// r14 (head-split) and r15 (degsort + persistent waves) both regressed —
// agg improvements are bracketed from three directions (latency depth,
// serial chain, tail imbalance); r13's form is the measured local optimum.
//  - padded-slot CSR (stride 96): scatter does its own counting.
//  - k_setup fuses {scatter, l1_transform, wconv, goff}. 7 dispatches.
//  - agg: dual-edge per iteration, f16 packed acc, defer-max THR=4.
// ---------------------------------------------------------------------------

typedef _Float16 half2v __attribute__((ext_vector_type(2)));
typedef _Float16 half8v __attribute__((ext_vector_type(8)));
typedef __attribute__((ext_vector_type(4))) float floatx4;

#define SLOT_STRIDE 96

template <int CPL> struct VecSel;
template <> struct VecSel<4> { using T = uint2; };
template <> struct VecSel<8> { using T = uint4; };

__device__ inline unsigned short f2h(float v) {
    return __builtin_bit_cast(unsigned short, (_Float16)v);
}
__device__ inline half2v u2h2(unsigned u) { return __builtin_bit_cast(half2v, u); }
__device__ inline unsigned h22u(half2v h) { return __builtin_bit_cast(unsigned, h); }
__device__ inline unsigned packh2(float a, float b) {
    half2v h; h[0] = (_Float16)a; h[1] = (_Float16)b;
    return h22u(h);
}

__device__ inline float fdot2f(half2v a, half2v b, float c) {
#if __has_builtin(__builtin_amdgcn_fdot2)
    return __builtin_amdgcn_fdot2(a, b, c, false);
#else
    return c + (float)a[0] * (float)b[0] + (float)a[1] * (float)b[1];
#endif
}

// ---------------- fused setup: scatter(padded CSR) + l1 + wconv + goff -----
// block ranges: [0,SC) scatter | [SC,SC+L1B) l1 | [.., +64) wconv | rest goff

#define L1_NODES 32

__global__ void k_setup(const int* __restrict__ ei, int E0, int N, int B,
                        int* __restrict__ counts, int* __restrict__ slots,
                        const int* __restrict__ batch, int* __restrict__ goff,
                        const float* __restrict__ x,
                        const float* __restrict__ Wl1, const float* __restrict__ bl1,
                        const float* __restrict__ Wr1, const float* __restrict__ br1,
                        unsigned short* __restrict__ xl1, unsigned short* __restrict__ xr1,
                        const float* __restrict__ Wl2, const float* __restrict__ Wr2,
                        unsigned short* __restrict__ Wlt, unsigned short* __restrict__ Wrt) {
    __shared__ char smem[8320];
    int E = E0 + N;
    int SC = (E + 255) >> 8;
    int L1B = (N + L1_NODES - 1) / L1_NODES;
    int bid = blockIdx.x;
    int t = threadIdx.x;  // 256

    if (bid < SC) {
        // ---- padded-slot scatter (counts zeroed beforehand) ----
        int e = bid * 256 + t;
        if (e >= E) return;
        int s, d;
        if (e < E0) { s = ei[e]; d = ei[E0 + e]; } else { s = e - E0; d = s; }
        int pos = atomicAdd(&counts[d], 1);
        if (pos < SLOT_STRIDE) slots[d * SLOT_STRIDE + pos] = s;
    } else if (bid < SC + L1B) {
        // ---- layer-1 transform: 32 nodes/block, f16x2 stores ----
        float (*xs)[9] = reinterpret_cast<float(*)[9]>(smem);
        int nb = (bid - SC) * L1_NODES;
        int h = t >> 7, p = t & 127;
        for (int i = t; i < L1_NODES * 9; i += 256) {
            int node = nb + i / 9;
            xs[i / 9][i % 9] = (node < N) ? x[node * 9 + i % 9] : 0.f;
        }
        __syncthreads();
        int c0 = 2 * p, c1 = 2 * p + 1;
        float wl0[9], wl1[9], wr0[9], wr1[9];
#pragma unroll
        for (int k = 0; k < 9; k++) {
            wl0[k] = Wl1[k * 256 + c0]; wl1[k] = Wl1[k * 256 + c1];
            wr0[k] = Wr1[k * 256 + c0]; wr1[k] = Wr1[k * 256 + c1];
        }
        float b0 = bl1[c0], b1 = bl1[c1], r0b = br1[c0], r1b = br1[c1];
        for (int j = h * 16; j < h * 16 + 16; j++) {
            int node = nb + j;
            if (node >= N) break;
            float a0 = b0, a1 = b1, r0 = r0b, r1 = r1b;
#pragma unroll
            for (int k = 0; k < 9; k++) {
                float xv = xs[j][k];
                a0 += xv * wl0[k]; a1 += xv * wl1[k];
                r0 += xv * wr0[k]; r1 += xv * wr1[k];
            }
            *reinterpret_cast<unsigned*>(xl1 + (size_t)node * 256 + c0) = packh2(a0, a1);
            *reinterpret_cast<unsigned*>(xr1 + (size_t)node * 256 + c0) = packh2(r0, r1);
        }
    } else if (bid < SC + L1B + 64) {
        // ---- weight transpose-convert: W[256][512] f32 -> Wt[512][256] f16
        unsigned short (*tile)[65] = reinterpret_cast<unsigned short(*)[65]>(smem);
        int idx = bid - SC - L1B;
        int tx = idx & 7, ty = (idx >> 3) & 3, tz = idx >> 5;
        const float* W = tz ? Wr2 : Wl2;
        unsigned short* Wt = tz ? Wrt : Wlt;
        int k0 = ty * 64, n0 = tx * 64;
        int tn = t & 63, tq = t >> 6;
#pragma unroll
        for (int i = 0; i < 16; i++) {
            int k = tq * 16 + i;
            tile[k][tn] = f2h(W[(size_t)(k0 + k) * 512 + n0 + tn]);
        }
        __syncthreads();
#pragma unroll
        for (int i = 0; i < 16; i++) {
            int nn = tq * 16 + i;
            Wt[(size_t)(n0 + nn) * 256 + k0 + tn] = tile[tn][nn];
        }
    } else {
        // ---- goff from sorted batch (transition detect) ----
        int n = (bid - SC - L1B - 64) * 256 + t;
        if (n >= N) return;
        int b = batch[n];
        int prev = (n == 0) ? -1 : batch[n - 1];
        for (int g = prev + 1; g <= b; g++) goff[g] = n;
        if (n == N - 1)
            for (int g = b + 1; g <= B; g++) goff[g] = N;
    }
}

// ---------------- wave-per-node GATv2 aggregation ----------------
// dual-edge iteration, f16 packed acc, defer-max THR=4.
// EPW=1: wave = node, 16 lanes/head, CPL channels per lane.

template <int CPL>
__global__ void k_gat_agg(const unsigned short* __restrict__ xl,
                          const unsigned short* __restrict__ xr,
                          const float* __restrict__ att, const float* __restrict__ bias,
                          const float* __restrict__ gamma, const float* __restrict__ beta,
                          const float* __restrict__ mean, const float* __restrict__ var,
                          const int* __restrict__ counts, const int* __restrict__ slots,
                          unsigned short* __restrict__ hout, int N) {
    const int HC = 64 * CPL;
    const int V = CPL / 2;
    using VecT = typename VecSel<CPL>::T;
    int wave = (blockIdx.x * blockDim.x + threadIdx.x) >> 6;
    int lane = threadIdx.x & 63;
    if (wave >= N) return;
    int n = wave;
    int cbase = lane * CPL;

    half2v xr2[V], at2[V], acc[V];
    {
        unsigned r[V];
        if constexpr (CPL == 8) {
            uint4 q = *reinterpret_cast<const uint4*>(xr + (size_t)n * HC + cbase);
            r[0] = q.x; r[1] = q.y; r[2] = q.z; r[3] = q.w;
        } else {
            uint2 q = *reinterpret_cast<const uint2*>(xr + (size_t)n * HC + cbase);
            r[0] = q.x; r[1] = q.y;
        }
#pragma unroll
        for (int v = 0; v < V; v++) {
            xr2[v] = u2h2(r[v]);
            at2[v][0] = (_Float16)att[cbase + 2 * v];
            at2[v][1] = (_Float16)att[cbase + 2 * v + 1];
            acc[v] = (half2v){(_Float16)0.f, (_Float16)0.f};
        }
    }
    const half2v c02 = {(_Float16)0.2f, (_Float16)0.2f};

    int deg = counts[n];
    deg = deg < SLOT_STRIDE ? deg : SLOT_STRIDE;
    const int* sl = slots + (size_t)n * SLOT_STRIDE;
    const unsigned short* xlb = xl + cbase;
    float m = -1e30f, l = 0.f;

    // prefetch first pair (deg >= 1 guaranteed by self-loop)
    VecT qA = *reinterpret_cast<const VecT*>(xlb + (size_t)sl[0] * HC);
    VecT qB = (deg > 1) ? *reinterpret_cast<const VecT*>(xlb + (size_t)sl[1] * HC) : qA;

    int slot = 0;
    while (slot + 1 < deg) {
        VecT ra = qA, rb = qB;
        int p2 = slot + 2 < deg ? slot + 2 : deg - 1;
        int p3 = slot + 3 < deg ? slot + 3 : deg - 1;
        qA = *reinterpret_cast<const VecT*>(xlb + (size_t)sl[p2] * HC);
        qB = *reinterpret_cast<const VecT*>(xlb + (size_t)sl[p3] * HC);

        half2v ah[V], bh[V];
        {
            unsigned ua[V], ub[V];
            if constexpr (CPL == 8) {
                ua[0] = ra.x; ua[1] = ra.y; ua[2] = ra.z; ua[3] = ra.w;
                ub[0] = rb.x; ub[1] = rb.y; ub[2] = rb.z; ub[3] = rb.w;
            } else {
                ua[0] = ra.x; ua[1] = ra.y;
                ub[0] = rb.x; ub[1] = rb.y;
            }
#pragma unroll
            for (int v = 0; v < V; v++) { ah[v] = u2h2(ua[v]); bh[v] = u2h2(ub[v]); }
        }
        float pa = 0.f, pb = 0.f;
#pragma unroll
        for (int v = 0; v < V; v++) {
            half2v ta = ah[v] + xr2[v];
            half2v la = __builtin_elementwise_max(ta, ta * c02);
            pa = fdot2f(la, at2[v], pa);
            half2v tb = bh[v] + xr2[v];
            half2v lb = __builtin_elementwise_max(tb, tb * c02);
            pb = fdot2f(lb, at2[v], pb);
        }
        pa += __shfl_xor(pa, 1);  pb += __shfl_xor(pb, 1);
        pa += __shfl_xor(pa, 2);  pb += __shfl_xor(pb, 2);
        pa += __shfl_xor(pa, 4);  pb += __shfl_xor(pb, 4);
        pa += __shfl_xor(pa, 8);  pb += __shfl_xor(pb, 8);
        float pm = fmaxf(pa, pb);
        if (__all(pm <= m + 4.f)) {
            float wa = __expf(pa - m), wb = __expf(pb - m);
            l += wa + wb;
            _Float16 wah = (_Float16)wa, wbh = (_Float16)wb;
            half2v wa2 = {wah, wah}, wb2 = {wbh, wbh};
#pragma unroll
            for (int v = 0; v < V; v++) {
                acc[v] = ah[v] * wa2 + acc[v];
                acc[v] = bh[v] * wb2 + acc[v];
            }
        } else {
            float mn = fmaxf(m, pm);
            float sc = __expf(m - mn);
            float wa = __expf(pa - mn), wb = __expf(pb - mn);
            l = l * sc + wa + wb;
            _Float16 sch = (_Float16)sc, wah = (_Float16)wa, wbh = (_Float16)wb;
            half2v sc2 = {sch, sch}, wa2 = {wah, wah}, wb2 = {wbh, wbh};
#pragma unroll
            for (int v = 0; v < V; v++) {
                acc[v] = ah[v] * wa2 + acc[v] * sc2;
                acc[v] = bh[v] * wb2 + acc[v];
            }
            m = mn;
        }
        slot += 2;
    }
    if (slot < deg) {
        // single remaining edge; clamped prefetch left its row in qA
        half2v ah[V];
        {
            unsigned ua[V];
            if constexpr (CPL == 8) {
                ua[0] = qA.x; ua[1] = qA.y; ua[2] = qA.z; ua[3] = qA.w;
            } else {
                ua[0] = qA.x; ua[1] = qA.y;
            }
#pragma unroll
            for (int v = 0; v < V; v++) ah[v] = u2h2(ua[v]);
        }
        float pa = 0.f;
#pragma unroll
        for (int v = 0; v < V; v++) {
            half2v ta = ah[v] + xr2[v];
            half2v la = __builtin_elementwise_max(ta, ta * c02);
            pa = fdot2f(la, at2[v], pa);
        }
        pa += __shfl_xor(pa, 1);
        pa += __shfl_xor(pa, 2);
        pa += __shfl_xor(pa, 4);
        pa += __shfl_xor(pa, 8);
        if (__all(pa <= m + 4.f)) {
            float wa = __expf(pa - m);
            l += wa;
            _Float16 wah = (_Float16)wa;
            half2v wa2 = {wah, wah};
#pragma unroll
            for (int v = 0; v < V; v++) acc[v] = ah[v] * wa2 + acc[v];
        } else {
            float mn = fmaxf(m, pa);
            float sc = __expf(m - mn);
            float wa = __expf(pa - mn);
            l = l * sc + wa;
            _Float16 sch = (_Float16)sc, wah = (_Float16)wa;
            half2v sc2 = {sch, sch}, wa2 = {wah, wah};
#pragma unroll
            for (int v = 0; v < V; v++) acc[v] = ah[v] * wa2 + acc[v] * sc2;
            m = mn;
        }
    }

    float inv = 1.f / l;
    unsigned ow[V];
#pragma unroll
    for (int v = 0; v < V; v++) {
        half2v o;
#pragma unroll
        for (int j = 0; j < 2; j++) {
            int c = cbase + 2 * v + j;
            float val = (float)acc[v][j] * inv + bias[c];
            val = (val - mean[c]) * rsqrtf(var[c] + 1e-5f) * gamma[c] + beta[c];
            o[j] = (_Float16)fmaxf(val, 0.f);
        }
        ow[v] = h22u(o);
    }
    unsigned short* dst = hout + (size_t)n * HC + cbase;
    if constexpr (CPL == 8)
        *reinterpret_cast<uint4*>(dst) = *reinterpret_cast<uint4*>(ow);
    else
        *reinterpret_cast<uint2*>(dst) = *reinterpret_cast<uint2*>(ow);
}

// ---------------- f16 MFMA GEMM: C[M,512] = A[M,256] @ Wt^T + bias --------

__global__ __launch_bounds__(256) void k_gemm_mfma(
    const unsigned short* __restrict__ A,    // [M][256] f16
    const unsigned short* __restrict__ Wlt,  // [512][256] f16
    const unsigned short* __restrict__ Wrt,
    const float* __restrict__ bl, const float* __restrict__ br,
    unsigned short* __restrict__ Cl, unsigned short* __restrict__ Cr,
    int M) {
    const int K = 256, NCOL = 512;
    __shared__ unsigned short lds[2][2][128 * 32];  // [buf][A|B][row*32+k], 32KB
    int side = blockIdx.z;
    const unsigned short* Bmat = side ? Wrt : Wlt;
    const float* bias = side ? br : bl;
    unsigned short* C = side ? Cr : Cl;
    int bm = blockIdx.y * 128, bn = blockIdx.x * 128;
    int t = threadIdx.x;
    int lane = t & 63;
    int wid = t >> 6;
    int wr = wid >> 1, wc = wid & 1;

    floatx4 acc[4][4];
#pragma unroll
    for (int m = 0; m < 4; m++)
#pragma unroll
        for (int n = 0; n < 4; n++) acc[m][n] = (floatx4){0.f, 0.f, 0.f, 0.f};

    auto stage = [&](int buf, int k0) {
#pragma unroll
        for (int i = 0; i < 2; i++) {
            int c = i * 256 + t;            // 16B chunk id, 512 chunks per tile
            int row = c >> 2;               // tile row (0..127)
            int kk = ((c & 3) << 3) ^ (((row >> 1) & 3) << 3);  // swizzled k-elems
            int gm = bm + row; gm = gm < M ? gm : M - 1;
            const unsigned short* gA = A + (size_t)gm * K + k0 + kk;
            __builtin_amdgcn_global_load_lds(
                (const __attribute__((address_space(1))) void*)gA,
                (__attribute__((address_space(3))) void*)&lds[buf][0][c * 8], 16, 0, 0);
            int gn = bn + row;
            const unsigned short* gB = Bmat + (size_t)gn * K + k0 + kk;
            __builtin_amdgcn_global_load_lds(
                (const __attribute__((address_space(1))) void*)gB,
                (__attribute__((address_space(3))) void*)&lds[buf][1][c * 8], 16, 0, 0);
        }
    };

    stage(0, 0);
    __syncthreads();
    int q = lane >> 4, rl = lane & 15;
    for (int ks = 0; ks < 8; ks++) {
        int buf = ks & 1;
        if (ks < 7) stage(buf ^ 1, (ks + 1) * 32);
        half8v a[4], b[4];
#pragma unroll
        for (int m = 0; m < 4; m++) {
            int row = wr * 64 + m * 16 + rl;
            int colb = (q * 16) ^ (((row >> 1) & 3) << 4);  // byte offset in row
            a[m] = *reinterpret_cast<const half8v*>(
                reinterpret_cast<const char*>(&lds[buf][0][0]) + row * 64 + colb);
        }
#pragma unroll
        for (int n = 0; n < 4; n++) {
            int row = wc * 64 + n * 16 + rl;
            int colb = (q * 16) ^ (((row >> 1) & 3) << 4);
            b[n] = *reinterpret_cast<const half8v*>(
                reinterpret_cast<const char*>(&lds[buf][1][0]) + row * 64 + colb);
        }
#pragma unroll
        for (int m = 0; m < 4; m++)
#pragma unroll
            for (int n = 0; n < 4; n++)
                acc[m][n] = __builtin_amdgcn_mfma_f32_16x16x32_f16(a[m], b[n], acc[m][n], 0, 0, 0);
        __syncthreads();
    }
    // epilogue: C/D layout col = lane&15, row = (lane>>4)*4 + reg
#pragma unroll
    for (int m = 0; m < 4; m++) {
#pragma unroll
        for (int n = 0; n < 4; n++) {
            int gn = bn + wc * 64 + n * 16 + rl;
            float bv = bias[gn];
#pragma unroll
            for (int r = 0; r < 4; r++) {
                int gm = bm + wr * 64 + m * 16 + q * 4 + r;
                if (gm < M) C[(size_t)gm * NCOL + gn] = f2h(acc[m][n][r] + bv);
            }
        }
    }
}

// ---------------- pooling phase 1 (B x 32 chunks, deterministic) -----------

#define POOL_CHUNKS 32

__global__ void k_pool_partial(const unsigned short* __restrict__ h2,
                               const int* __restrict__ goff,
                               float* __restrict__ partial) {
    int g = blockIdx.x, c = blockIdx.y;
    int t = threadIdx.x;  // 256, each handles 2 cols via uint load
    int n0 = goff[g], n1 = goff[g + 1];
    int len = n1 - n0;
    int c0 = n0 + (int)(((long long)len * c) / POOL_CHUNKS);
    int c1 = n0 + (int)(((long long)len * (c + 1)) / POOL_CHUNKS);
    float s0 = 0.f, s1 = 0.f;
    for (int n = c0; n < c1; n++) {
        half2v h = u2h2(*reinterpret_cast<const unsigned*>(h2 + (size_t)n * 512 + t * 2));
        s0 += (float)h[0]; s1 += (float)h[1];
    }
    float* p = partial + ((size_t)g * POOL_CHUNKS + c) * 512;
    p[t * 2] = s0;
    p[t * 2 + 1] = s1;
}

// ---------------- fused pool-combine + MLP head (one block per graph) ------

__global__ void k_pool_head(const float* __restrict__ partial,
                            const int* __restrict__ goff,
                            const float* __restrict__ gf,
                            const float* __restrict__ W1, const float* __restrict__ b1,
                            const float* __restrict__ W2, const float* __restrict__ b2,
                            float* __restrict__ out) {
    int g = blockIdx.x;
    int t = threadIdx.x;  // 512
    __shared__ float z[532];
    __shared__ float red[128];
    float s = 0.f;
#pragma unroll
    for (int c = 0; c < POOL_CHUNKS; c++)
        s += partial[((size_t)g * POOL_CHUNKS + c) * 512 + t];
    float inv = 1.f / fmaxf((float)(goff[g + 1] - goff[g]), 1.f);
    z[t] = s * inv;
    if (t < 20) z[512 + t] = gf[g * 20 + t];
    __syncthreads();
    if (t < 128) {
        float a = b1[t];
        for (int k = 0; k < 532; k++) a += z[k] * W1[k * 128 + t];
        red[t] = fmaxf(a, 0.f) * W2[t];
    }
    __syncthreads();
    if (t < 64) {
        float v = red[t] + red[t + 64];
#pragma unroll
        for (int sdown = 32; sdown; sdown >>= 1) v += __shfl_down(v, sdown);
        if (t == 0) out[g] = v + b2[0];
    }
}

// ---------------------------------------------------------------------------

extern "C" void kernel_launch(void* const* d_in, const int* in_sizes, int n_in,
                              void* d_out, int out_size, void* d_ws, size_t ws_size,
                              hipStream_t stream) {
    const float* x       = (const float*)d_in[0];
    const float* gfeat   = (const float*)d_in[1];
    const int*   ei      = (const int*)d_in[2];
    const int*   batch   = (const int*)d_in[3];
    const float* W_l1    = (const float*)d_in[4];
    const float* b_l1    = (const float*)d_in[5];
    const float* W_r1    = (const float*)d_in[6];
    const float* b_r1    = (const float*)d_in[7];
    const float* att1    = (const float*)d_in[8];
    const float* bias1   = (const float*)d_in[9];
    const float* bn1_g   = (const float*)d_in[10];
    const float* bn1_b   = (const float*)d_in[11];
    const float* bn1_m   = (const float*)d_in[12];
    const float* bn1_v   = (const float*)d_in[13];
    const float* W_l2    = (const float*)d_in[14];
    const float* b_l2    = (const float*)d_in[15];
    const float* W_r2    = (const float*)d_in[16];
    const float* b_r2    = (const float*)d_in[17];
    const float* att2    = (const float*)d_in[18];
    const float* bias2   = (const float*)d_in[19];
    const float* bn2_g   = (const float*)d_in[20];
    const float* bn2_b   = (const float*)d_in[21];
    const float* bn2_m   = (const float*)d_in[22];
    const float* bn2_v   = (const float*)d_in[23];
    const float* fc1_W   = (const float*)d_in[24];
    const float* fc1_b   = (const float*)d_in[25];
    const float* fc2_W   = (const float*)d_in[26];
    const float* fc2_b   = (const float*)d_in[27];
    float* out = (float*)d_out;

    const int N  = in_sizes[0] / 9;   // 20000
    const int B  = in_sizes[1] / 20;  // 64
    const int E0 = in_sizes[2] / 2;   // 320000
    const int E  = E0 + N;

    // ---- workspace layout (bytes) ----
    char* ws = (char*)d_ws;
    const size_t SZ256 = (size_t)N * 256 * 2;  // 10.24 MB (f16)
    const size_t SZ512 = (size_t)N * 512 * 2;  // 20.48 MB (f16)
    unsigned short* xl1 = (unsigned short*)(ws);
    unsigned short* xr1 = (unsigned short*)(ws + SZ256);
    unsigned short* h1  = (unsigned short*)(ws + 2 * SZ256);
    unsigned short* xl2 = (unsigned short*)(ws + 3 * SZ256);
    unsigned short* xr2 = (unsigned short*)(ws + 3 * SZ256 + SZ512);
    unsigned short* h2  = (unsigned short*)(ws + 3 * SZ256 + 2 * SZ512);
    size_t o = 3 * SZ256 + 3 * SZ512;                       // 92,160,000
    unsigned short* Wlt = (unsigned short*)(ws + o);        // 512*256*2 = 262144
    unsigned short* Wrt = (unsigned short*)(ws + o + 262144);
    size_t oi = o + 2 * 262144;                             // 92,684,288
    int* counts = (int*)(ws + oi);                          // N ints (zeroed)
    int* goff   = (int*)(ws + oi + 80000);                  // B+1 ints
    int* slots  = (int*)(ws + oi + 80000 + 384);            // N*96 ints = 7.68MB
    size_t op = oi + 80000 + 384 + (size_t)N * SLOT_STRIDE * 4;
    float* partial = (float*)(ws + op);                     // B*32*512 f32 = 4MB
    (void)ws_size; (void)n_in; (void)out_size;

    // zero only counts (the single atomically-built array)
    (void)hipMemsetAsync(ws + oi, 0, 80000, stream);

    // fused setup: scatter + l1_transform + wconv + goff
    int SC = (E + 255) / 256;
    int L1B = (N + L1_NODES - 1) / L1_NODES;
    int GB = (N + 255) / 256;
    k_setup<<<SC + L1B + 64 + GB, 256, 0, stream>>>(
        ei, E0, N, B, counts, slots, batch, goff,
        x, W_l1, b_l1, W_r1, b_r1, xl1, xr1, W_l2, W_r2, Wlt, Wrt);

    // layer 1 aggregation (HC=256 -> CPL=4)
    k_gat_agg<4><<<(N * 64 + 255) / 256, 256, 0, stream>>>(
        xl1, xr1, att1, bias1, bn1_g, bn1_b, bn1_m, bn1_v, counts, slots, h1, N);

    // layer 2 transforms: one dispatch, z selects W_l / W_r
    dim3 ggrid(512 / 128, (N + 127) / 128, 2);
    k_gemm_mfma<<<ggrid, 256, 0, stream>>>(h1, Wlt, Wrt, b_l2, b_r2, xl2, xr2, N);

    // layer 2 aggregation (HC=512 -> CPL=8)
    k_gat_agg<8><<<(N * 64 + 255) / 256, 256, 0, stream>>>(
        xl2, xr2, att2, bias2, bn2_g, bn2_b, bn2_m, bn2_v, counts, slots, h2, N);

    // pool (partial) + fused combine+head
    k_pool_partial<<<dim3(B, POOL_CHUNKS), 256, 0, stream>>>(h2, goff, partial);
    k_pool_head<<<B, 512, 0, stream>>>(partial, goff, gfeat,
                                       fc1_W, fc1_b, fc2_W, fc2_b, out);
}